// Round 10
// baseline (27.927 us; speedup 1.0000x reference)
//
#include <hip/hip_runtime.h>

// Problem geometry (fixed by reference):
//   preds : (B=2, T=8, E=16, H=128, W=256) f32, idx ((b*8+t)*16+e)*HW + hw
//   target: (B=2, T=8, 1,    H=128, W=256) f32
//   output: scalar f32
//
// Regime notes (R1-R9 evidence):
//  - Partial kernel is near its BW/latency envelope: traffic cut (R4),
//    load-instr cut (R8), VALU cut (R9) all ~neutral. ~76% of HBM ceiling
//    if partial ~8us.
//  - Best mapping: t-pair per thread, k in low 2 lane bits, shfl boundary
//    exchange (R4, 13.48us). One-t mappings +3us (R7/R8); LDS exchange +7us
//    (R3); fused last-block tail spills cur[] to scratch (R5/R6, VGPR 20-24,
//    3-5x). No forced min-waves (R5).
//  - R10: kill the expensive 1-block final reduce. Deterministic Q32
//    fixed-point integer atomicAdd per block (integer adds commute exactly
//    -> bit-identical every replay); kernel 2 = 1 thread converting to f32.
#define HW    32768   // 128*256
#define T_DIM 8
#define E_DIM 16
#define NPOS  65536   // B * HW
#define BLK   256
#define NTHREADS 262144                 // B * HW * 4 t-pairs
#define NBLK  (NTHREADS / BLK)          // 1024

// term1/16 - term2core/256 for one (b,t,hw): p[16] vs tgt
__device__ __forceinline__ float crps_term(const float* p, float tgt) {
    float t1 = 0.f;
#pragma unroll
    for (int e = 0; e < E_DIM; ++e)
        t1 += fabsf(p[e] - tgt);
    float s = 0.f;
#pragma unroll
    for (int i = 0; i < E_DIM; ++i)
#pragma unroll
        for (int j = i + 1; j < E_DIM; ++j)
            s += fabsf(p[i] - p[j]);
    return t1 * (1.f / 16.f) - s * (1.f / 256.f);
}

// Thread (b, hw, k) owns t in {2k, 2k+1}; k lives in the low 2 lane bits so
// the thread holding pair k-1 (same hw) is lane-1 -> boundary temporal diffs
// via __shfl. Every preds/target element is loaded exactly once.
__global__ __launch_bounds__(BLK) void crps_partial(const float* __restrict__ preds,
                                                    const float* __restrict__ target,
                                                    unsigned long long* __restrict__ acc64) {
    const int n  = blockIdx.x * BLK + threadIdx.x;   // 18 bits
    const int k  = n & 3;                            // t-pair 0..3 (lane bits)
    const int hw = (n >> 2) & (HW - 1);              // 15 bits
    const int b  = n >> 17;                          // 0..1
    const int t0 = 2 * k;

    const float* pb = preds  + hw;
    const float* tb = target + hw;

    float cur0[E_DIM], cur1[E_DIM];
#pragma unroll
    for (int e = 0; e < E_DIM; ++e)
        cur0[e] = pb[((size_t)((b * T_DIM + t0) * E_DIM) + e) * HW];
#pragma unroll
    for (int e = 0; e < E_DIM; ++e)
        cur1[e] = pb[((size_t)((b * T_DIM + t0 + 1) * E_DIM) + e) * HW];
    const float tgt0 = tb[(size_t)(b * T_DIM + t0) * HW];
    const float tgt1 = tb[(size_t)(b * T_DIM + t0 + 1) * HW];

    // boundary transition t=2k-1 -> 2k: pull neighbor lane's cur1
    const int lane = threadIdx.x & 63;
    const int src  = (lane > 0) ? (lane - 1) : 0;
    float tacc = 0.f;
#pragma unroll
    for (int e = 0; e < E_DIM; ++e) {
        float pv = __shfl(cur1[e], src, 64);         // exec-sync, DS pipe
        if (k > 0)
            tacc += fabsf(cur0[e] - pv);
    }
    // within-pair transition t=2k -> 2k+1
#pragma unroll
    for (int e = 0; e < E_DIM; ++e)
        tacc += fabsf(cur1[e] - cur0[e]);

    float acc = crps_term(cur0, tgt0) + crps_term(cur1, tgt1);

    // per-(b,hw) scaling: crps terms averaged over 8 t; temporal over 112
    float v = acc * (1.f / 8.f) + tacc * (0.1f / 112.f);

    // block reduction
    __shared__ float rlds[4];
#pragma unroll
    for (int off = 32; off; off >>= 1)
        v += __shfl_down(v, off, 64);
    const int wid = threadIdx.x >> 6;
    if (lane == 0) rlds[wid] = v;
    __syncthreads();

    if (threadIdx.x == 0) {
        float bsum = rlds[0] + rlds[1] + rlds[2] + rlds[3];
        // Q32 fixed point: exact integer accumulation -> deterministic
        long long q = llrint((double)bsum * 4294967296.0);
        atomicAdd(acc64, (unsigned long long)q);
    }
}

__global__ void crps_final(const unsigned long long* __restrict__ acc64,
                           float* __restrict__ out) {
    long long q = (long long)*acc64;
    out[0] = (float)((double)q * (1.0 / 4294967296.0) * (1.0 / (double)NPOS));
}

extern "C" void kernel_launch(void* const* d_in, const int* in_sizes, int n_in,
                              void* d_out, int out_size, void* d_ws, size_t ws_size,
                              hipStream_t stream) {
    const float* preds  = (const float*)d_in[0];
    const float* target = (const float*)d_in[1];
    float* out = (float*)d_out;
    unsigned long long* acc64 = (unsigned long long*)d_ws;

    hipMemsetAsync(acc64, 0, sizeof(unsigned long long), stream); // capture-legal
    crps_partial<<<NBLK, BLK, 0, stream>>>(preds, target, acc64);
    crps_final<<<1, 1, 0, stream>>>(acc64, out);
}